// Round 7
// baseline (515.622 us; speedup 1.0000x reference)
//
#include <hip/hip_runtime.h>
#include <cstdint>
#include <cstddef>

typedef __bf16 bf16;
typedef _Float16 f16;
typedef __attribute__((ext_vector_type(8))) __bf16 bf16x8;
typedef __attribute__((ext_vector_type(4))) __bf16 bf16x4;
typedef __attribute__((ext_vector_type(4))) float f32x4;
typedef __attribute__((ext_vector_type(2))) float f32x2;
typedef __attribute__((ext_vector_type(2))) uint32_t u32x2;

#define DINL __device__ __forceinline__

DINL float wred(float v) {
#pragma unroll
  for (int m = 32; m; m >>= 1) v += __shfl_xor(v, m, 64);
  return v;
}

// chunk-level XOR swizzle (16B granules within a 128B row), returns byte offset
DINL int swz(int r) { return ((r ^ (r >> 2)) & 7) << 4; }
// same swizzle as 16B-chunk index
DINL int swzc(int r) { return (r ^ (r >> 2)) & 7; }

// ---------- zero the fp32 accumulator (capture-safe) ----------
__global__ void k_zero(float* __restrict__ p) {
  p[blockIdx.x * 256 + threadIdx.x] = 0.f;
}

// ---------- coords: off = qf@w_off + b_off ; roi math ; softmax lw ----------
__global__ void k_coords(const float* __restrict__ qf, const float* __restrict__ roi,
                         const float* __restrict__ w_off, const float* __restrict__ b_off,
                         float* __restrict__ coords) {
  int bn = blockIdx.x;
  int t = threadIdx.x; // 0..383
  __shared__ float qs[256];
  __shared__ float offs[384];
  if (t < 256) qs[t] = qf[(size_t)bn * 256 + t];
  __syncthreads();
  float acc = b_off[t];
  for (int k = 0; k < 256; k++) acc += qs[k] * w_off[k * 384 + t];
  offs[t] = acc;
  __syncthreads();
  if (t < 128) {
    float ox = offs[t * 3 + 0], oy = offs[t * 3 + 1], oz = offs[t * 3 + 2];
    float cx = roi[bn * 4 + 0], cy = roi[bn * 4 + 1];
    float z  = roi[bn * 4 + 2], rr = roi[bn * 4 + 3];
    float sx = cx + ox * exp2f(z - 0.5f * rr);
    float sy = cy + oy * exp2f(z + 0.5f * rr);
    float lvl = z + oz;
    float e[4], mx = -1e30f;
#pragma unroll
    for (int l = 0; l < 4; l++) {
      float d = lvl - 3.0f - (float)l;
      e[l] = -d * d * 0.5f;           // TAU = 2
      mx = fmaxf(mx, e[l]);
    }
    float s = 0.f;
#pragma unroll
    for (int l = 0; l < 4; l++) { e[l] = expf(e[l] - mx); s += e[l]; }
    float inv = 1.f / s;
    float* o = coords + ((size_t)bn * 128 + t) * 6;
    o[0] = sx; o[1] = sy;
#pragma unroll
    for (int l = 0; l < 4; l++) o[2 + l] = e[l] * inv;
  }
}

// ---------- transpose (b,g) slabs -> channel-last (HW_total, 64) f16 ----------
// BATCHED: all 16 global loads into v[16] (MLP exposed; prior version had
// VGPR=8 -> serialized vmcnt chains, 90 us at 5% VALU). Then cvt+LDS writes,
// barrier, batched LDS reads -> 8B stores.
__global__ __launch_bounds__(256) void k_xpose(
    const float* __restrict__ x0, const float* __restrict__ x1,
    const float* __restrict__ x2, const float* __restrict__ x3,
    f16* __restrict__ xt, int bg0, size_t slab) {
  const int HWl[4]  = {67200, 16800, 4200, 1050};
  const int RB[4]   = {0, 67200, 84000, 88200};
  const float* xs[4] = {x0, x1, x2, x3};
  int bx = blockIdx.x;
  int l, t0;
  if (bx < 525)      { l = 0; t0 = 0; }
  else if (bx < 657) { l = 1; t0 = 525; }
  else if (bx < 690) { l = 2; t0 = 657; }
  else               { l = 3; t0 = 690; }
  int HW = HWl[l];
  int sp0 = (bx - t0) * 128;
  int bg = bg0 + blockIdx.z;
  int b = bg >> 2, g = bg & 3;
  const float* src = xs[l] + (size_t)(b * 256 + g * 64) * HW;
  __shared__ f16 tile[128 * 66];            // [sp][ch], pitch 66 f16 (132 B rows)
  int tid = threadIdx.x;
  int lane = tid & 63, wv = tid >> 6;
  int sp = sp0 + lane * 2;
  if (sp < HW) {                            // HW even for all levels
    f32x2 v[16];
#pragma unroll
    for (int j = 0; j < 16; j++)
      v[j] = *(const f32x2*)(src + (size_t)(wv * 16 + j) * HW + sp);
#pragma unroll
    for (int j = 0; j < 16; j++) {
      int ch = wv * 16 + j;
      tile[(lane * 2 + 0) * 66 + ch] = (f16)v[j][0];
      tile[(lane * 2 + 1) * 66 + ch] = (f16)v[j][1];
    }
  }
  __syncthreads();
  f16* dst = xt + slab * blockIdx.z + (size_t)(RB[l] + sp0) * 64;
  int c4 = tid & 15, srow = tid >> 4;
  const uint32_t* tp = (const uint32_t*)(&tile[0]);   // 33 dwords per row
  uint32_t pk[16];
#pragma unroll
  for (int it = 0; it < 8; it++) {
    int s = it * 16 + srow;
    pk[it * 2 + 0] = tp[s * 33 + c4 * 2];
    pk[it * 2 + 1] = tp[s * 33 + c4 * 2 + 1];
  }
#pragma unroll
  for (int it = 0; it < 8; it++) {
    int s = it * 16 + srow;
    if (sp0 + s < HW) {
      u32x2 q; q[0] = pk[it * 2]; q[1] = pk[it * 2 + 1];
      *(u32x2*)(dst + (size_t)s * 64 + c4 * 4) = q;
    }
  }
}

// ---------- sampling from channel-last f16 (FALLBACK path only) ----------
__global__ __launch_bounds__(256) void k_sample2(
    const float* __restrict__ coords, const f16* __restrict__ xt,
    bf16* __restrict__ sampled, int bg0, size_t slab) {
  const int   Wl[4] = {336, 168, 84, 42};
  const int   Hl[4] = {200, 100, 50, 25};
  const int   RB[4] = {0, 67200, 84000, 88200};
  const float IS[4] = {0.25f, 0.125f, 0.0625f, 0.03125f};
  int bg = bg0 + blockIdx.z;
  int b = bg >> 2, g = bg & 3;
  int bn = b * 300 + blockIdx.x;
  const f16* xts = xt + slab * blockIdx.z;
  int c = threadIdx.x & 63, pp = threadIdx.x >> 6;
#pragma unroll
  for (int p8i = 0; p8i < 4; p8i++) {
    int p8 = blockIdx.y * 4 + p8i;
    int p = p8 * 4 + pp;
    const float* cd = coords + ((size_t)bn * 128 + g * 32 + p) * 6;
    float sx = cd[0], sy = cd[1];
    float acc = 0.f;
#pragma unroll
    for (int l = 0; l < 4; l++) {
      float wl = cd[2 + l];
      int W = Wl[l], H = Hl[l];
      float xf = sx * IS[l] - 0.5f;
      float yf = sy * IS[l] - 0.5f;
      float xx0 = floorf(xf), yy0 = floorf(yf);
      float fx = xf - xx0, fy = yf - yy0;
      int xi = (int)xx0, yi = (int)yy0;
      const f16* base = xts + (size_t)RB[l] * 64 + c;
      float v = 0.f;
      if (xi >= 0     && xi < W     && yi >= 0     && yi < H)
        v += (1.f - fx) * (1.f - fy) * (float)base[(size_t)(yi * W + xi) * 64];
      if (xi + 1 >= 0 && xi + 1 < W && yi >= 0     && yi < H)
        v += fx * (1.f - fy) * (float)base[(size_t)(yi * W + xi + 1) * 64];
      if (xi >= 0     && xi < W     && yi + 1 >= 0 && yi + 1 < H)
        v += (1.f - fx) * fy * (float)base[(size_t)((yi + 1) * W + xi) * 64];
      if (xi + 1 >= 0 && xi + 1 < W && yi + 1 >= 0 && yi + 1 < H)
        v += fx * fy * (float)base[(size_t)((yi + 1) * W + xi + 1) * 64];
      acc += wl * v;
    }
    sampled[(((size_t)bn * 4 + g) * 32 + p) * 64 + c] = (bf16)acc;
  }
}

// ---------- MFMA params GEMM: pchunk[m][a] = sum_k qf[m_off+m][k]*pg_w[k][a] + pg_b[a]
__global__ __launch_bounds__(256) void k_params_mfma(
    const float* __restrict__ qf, const float* __restrict__ pg_w,
    const float* __restrict__ pg_b, bf16* __restrict__ pchunk,
    int m_off, int m_cnt) {
  __shared__ char sA[8192];    // [64 rows][128 B]
  __shared__ char sW[32768];   // [256 n-rows][128 B]
  const int tid = threadIdx.x;
  const int w = tid >> 6, l = tid & 63;
  const int lr = l & 15, lq = l >> 4;
  const int m0 = blockIdx.y * 64;
  const int n0 = blockIdx.x * 256;

  f32x4 acc[4][4];
#pragma unroll
  for (int i = 0; i < 4; i++)
#pragma unroll
    for (int j = 0; j < 4; j++) acc[i][j] = (f32x4)(0.f);

  for (int kt = 0; kt < 4; kt++) {
    const int kb = kt * 64;

#pragma unroll
    for (int i = 0; i < 2; i++) {
      int c = tid * 2 + i;                  // 16B chunk id, 0..511
      int r = c >> 3, kc = c & 7;
      int gm = m0 + r; gm = (gm < m_cnt) ? gm : (m_cnt - 1);
      const float* src = qf + (size_t)(m_off + gm) * 256 + kb + kc * 8;
      f32x4 v0 = *(const f32x4*)src;
      f32x4 v1 = *(const f32x4*)(src + 4);
      bf16x8 t = {(bf16)v0[0], (bf16)v0[1], (bf16)v0[2], (bf16)v0[3],
                  (bf16)v1[0], (bf16)v1[1], (bf16)v1[2], (bf16)v1[3]};
      *(bf16x8*)(sA + r * 128 + ((kc << 4) ^ swz(r))) = t;
    }

#pragma unroll
    for (int i = 0; i < 4; i++) {
      int kblk = i * 4 + w;                 // 0..15, k = kblk*4 + 0..3
      const float* src = pg_w + (size_t)(kb + kblk * 4) * 32768 + n0 + l * 4;
      f32x4 r0 = *(const f32x4*)(src);
      f32x4 r1 = *(const f32x4*)(src + 32768);
      f32x4 r2 = *(const f32x4*)(src + 65536);
      f32x4 r3 = *(const f32x4*)(src + 98304);
      int chv = (kblk >> 1) << 4;
      int sub = (kblk & 1) * 8;
#pragma unroll
      for (int j = 0; j < 4; j++) {
        int n = l * 4 + j;
        bf16x4 t = {(bf16)r0[j], (bf16)r1[j], (bf16)r2[j], (bf16)r3[j]};
        *(bf16x4*)(sW + n * 128 + (chv ^ swz(n)) + sub) = t;
      }
    }
    __syncthreads();

#pragma unroll
    for (int ks = 0; ks < 2; ks++) {
      bf16x8 a[4], b[4];
      int ch = (ks * 4 + lq) << 4;
#pragma unroll
      for (int i = 0; i < 4; i++) {
        int row = i * 16 + lr;
        a[i] = *(const bf16x8*)(sA + row * 128 + (ch ^ swz(row)));
      }
#pragma unroll
      for (int j = 0; j < 4; j++) {
        int nn = w * 64 + j * 16 + lr;
        b[j] = *(const bf16x8*)(sW + nn * 128 + (ch ^ swz(nn)));
      }
#pragma unroll
      for (int i = 0; i < 4; i++)
#pragma unroll
        for (int j = 0; j < 4; j++)
          acc[i][j] = __builtin_amdgcn_mfma_f32_16x16x32_bf16(a[i], b[j], acc[i][j], 0, 0, 0);
    }
    __syncthreads();
  }

#pragma unroll
  for (int i = 0; i < 4; i++) {
#pragma unroll
    for (int r = 0; r < 4; r++) {
      int m = m0 + i * 16 + lq * 4 + r;
      if (m < m_cnt) {
        bf16* dst = pchunk + (size_t)m * 32768 + n0 + w * 64 + lr;
#pragma unroll
        for (int j = 0; j < 4; j++) {
          int n = n0 + w * 64 + j * 16 + lr;
          dst[j * 16] = (bf16)(acc[i][j][r] + pg_b[n]);
        }
      }
    }
  }
}

// ---------- FUSED gather + MFMA mixing: one block per (bn, g) ----------
// Gathers its own 32p x 64c tile from xt into swizzled LDS (replacing
// k_sample2 + the `sampled` round-trip), then runs the proven MFMA mix.
__global__ __launch_bounds__(256) void k_mix_fused(
    const float* __restrict__ coords, const f16* __restrict__ xt,
    bf16* __restrict__ params, size_t slab) {
  const int   Wl[4] = {336, 168, 84, 42};
  const int   Hl[4] = {200, 100, 50, 25};
  const int   RB[4] = {0, 67200, 84000, 88200};
  const float IS[4] = {0.25f, 0.125f, 0.0625f, 0.03125f};
  int bn = blockIdx.x, g = blockIdx.y;
  int b = (bn >= 300) ? 1 : 0;
  int tid = threadIdx.x;
  const int w = tid >> 6, l = tid & 63;
  const int lr = l & 15, lq = l >> 4;
  __shared__ char mt[8192];                       // Mt[d=64][128B], swizzled
  __shared__ char samp_s[4096];                   // [32p][128B], swizzled bf16
  __shared__ alignas(16) bf16 h1t[64 * 40];       // h1t[d][p], 80B row pitch
  __shared__ float red[8];
  bf16* pr = params + (size_t)bn * 32768 + (size_t)g * 8192;
  const f16* xts = xt + slab * (size_t)(b * 4 + g);

  // ---- stage Mt: M[c][d] -> Mt[d][c] (issue early; overlaps gather) ----
  {
    int cblk = tid >> 4, dblk = tid & 15;
    const bf16* srcm = pr + cblk * 256 + dblk * 4;
    bf16x4 r0 = *(const bf16x4*)(srcm);
    bf16x4 r1 = *(const bf16x4*)(srcm + 64);
    bf16x4 r2 = *(const bf16x4*)(srcm + 128);
    bf16x4 r3 = *(const bf16x4*)(srcm + 192);
    int chv = (cblk >> 1) << 4, sub = (cblk & 1) * 8;
#pragma unroll
    for (int j = 0; j < 4; j++) {
      int d = dblk * 4 + j;
      bf16x4 t = {r0[j], r1[j], r2[j], r3[j]};
      *(bf16x4*)(mt + d * 128 + (chv ^ swz(d)) + sub) = t;
    }
  }

  // ---- gather: 8 points per thread (p = it*4 + w, c = l) ----
#pragma unroll
  for (int it = 0; it < 8; it++) {
    int p = it * 4 + w;
    const float* cd = coords + ((size_t)bn * 128 + g * 32 + p) * 6;
    float sx = cd[0], sy = cd[1];
    float acc = 0.f;
#pragma unroll
    for (int lv = 0; lv < 4; lv++) {
      float wl = cd[2 + lv];
      int W = Wl[lv], H = Hl[lv];
      float xf = sx * IS[lv] - 0.5f;
      float yf = sy * IS[lv] - 0.5f;
      float xx0 = floorf(xf), yy0 = floorf(yf);
      float fx = xf - xx0, fy = yf - yy0;
      int xi = (int)xx0, yi = (int)yy0;
      const f16* base = xts + (size_t)RB[lv] * 64 + l;
      float v = 0.f;
      if (xi >= 0     && xi < W     && yi >= 0     && yi < H)
        v += (1.f - fx) * (1.f - fy) * (float)base[(size_t)(yi * W + xi) * 64];
      if (xi + 1 >= 0 && xi + 1 < W && yi >= 0     && yi < H)
        v += fx * (1.f - fy) * (float)base[(size_t)(yi * W + xi + 1) * 64];
      if (xi >= 0     && xi < W     && yi + 1 >= 0 && yi + 1 < H)
        v += (1.f - fx) * fy * (float)base[(size_t)((yi + 1) * W + xi) * 64];
      if (xi + 1 >= 0 && xi + 1 < W && yi + 1 >= 0 && yi + 1 < H)
        v += fx * fy * (float)base[(size_t)((yi + 1) * W + xi + 1) * 64];
      acc += wl * v;
    }
    // swizzled write: row p, logical 16B chunk l>>3, within-chunk f16 slot l&7
    *(bf16*)(samp_s + p * 128 + (((l >> 3) ^ swzc(p)) << 4) + (l & 7) * 2) = (bf16)acc;
  }
  __syncthreads();

  // ---- step 1: 4 MFMAs (2 m-frags x 2 k-steps), wave's d-slice ----
  f32x4 acc1[2];
  acc1[0] = (f32x4)(0.f); acc1[1] = (f32x4)(0.f);
  const int dd = w * 16 + lr;
#pragma unroll
  for (int ks = 0; ks < 2; ks++) {
    bf16x8 bfr = *(const bf16x8*)(mt + dd * 128 + ((((ks << 2) | lq) << 4) ^ swz(dd)));
#pragma unroll
    for (int i = 0; i < 2; i++) {
      int row = i * 16 + lr;
      bf16x8 a = *(const bf16x8*)(samp_s + row * 128 +
                                  ((((ks << 2) | lq) ^ swzc(row)) << 4));
      acc1[i] = __builtin_amdgcn_mfma_f32_16x16x32_bf16(a, bfr, acc1[i], 0, 0, 0);
    }
  }

  // ---- LN1 over 2048 + relu, write h1t[d][p] bf16 ----
  {
    float s = 0.f, ss = 0.f;
#pragma unroll
    for (int i = 0; i < 2; i++)
#pragma unroll
      for (int r = 0; r < 4; r++) { float v = acc1[i][r]; s += v; ss += v * v; }
    s = wred(s); ss = wred(ss);
    if (l == 0) { red[w] = s; red[4 + w] = ss; }
    __syncthreads();
    s = red[0] + red[1] + red[2] + red[3];
    ss = red[4] + red[5] + red[6] + red[7];
    float mean = s * (1.f / 2048.f);
    float var = ss * (1.f / 2048.f) - mean * mean;
    float rs = rsqrtf(fmaxf(var, 0.f) + 1e-5f);
#pragma unroll
    for (int i = 0; i < 2; i++)
#pragma unroll
      for (int r = 0; r < 4; r++) {
        float v = (acc1[i][r] - mean) * rs;
        v = v > 0.f ? v : 0.f;
        int p = i * 16 + lq * 4 + r;
        h1t[dd * 40 + p] = (bf16)v;
      }
  }
  __syncthreads();

  // ---- step 2: 8 MFMAs (2 m-frags x 4 n-frags), wave's o-slice ----
  f32x4 acc2[2][4];
#pragma unroll
  for (int i = 0; i < 2; i++)
#pragma unroll
    for (int j = 0; j < 4; j++) acc2[i][j] = (f32x4)(0.f);
  bf16x8 b2[4];
#pragma unroll
  for (int j = 0; j < 4; j++)
    b2[j] = *(const bf16x8*)(&h1t[(j * 16 + lr) * 40 + lq * 8]);
#pragma unroll
  for (int i = 0; i < 2; i++) {
    int o = w * 32 + i * 16 + lr;
    bf16x8 a = *(const bf16x8*)(pr + 4096 + o * 32 + lq * 8);
#pragma unroll
    for (int j = 0; j < 4; j++)
      acc2[i][j] = __builtin_amdgcn_mfma_f32_16x16x32_bf16(a, b2[j], acc2[i][j], 0, 0, 0);
  }

  // ---- LN2 over 8192 + relu, store bf16 in place (o*64+d) ----
  {
    float s = 0.f, ss = 0.f;
#pragma unroll
    for (int i = 0; i < 2; i++)
#pragma unroll
      for (int j = 0; j < 4; j++)
#pragma unroll
        for (int r = 0; r < 4; r++) { float v = acc2[i][j][r]; s += v; ss += v * v; }
    s = wred(s); ss = wred(ss);
    if (l == 0) { red[w] = s; red[4 + w] = ss; }
    __syncthreads();   // also orders all waves' S reads before in-place overwrite
    s = red[0] + red[1] + red[2] + red[3];
    ss = red[4] + red[5] + red[6] + red[7];
    float mean = s * (1.f / 8192.f);
    float var = ss * (1.f / 8192.f) - mean * mean;
    float rs = rsqrtf(fmaxf(var, 0.f) + 1e-5f);
#pragma unroll
    for (int i = 0; i < 2; i++)
#pragma unroll
      for (int r = 0; r < 4; r++) {
        int o = w * 32 + i * 16 + lq * 4 + r;
#pragma unroll
        for (int j = 0; j < 4; j++) {
          float v = (acc2[i][j][r] - mean) * rs;
          v = v > 0.f ? v : 0.f;
          pr[o * 64 + j * 16 + lr] = (bf16)v;
        }
      }
  }
}

// ---------- MFMA mixing from precomputed `sampled` (FALLBACK path only) ----------
__global__ __launch_bounds__(256) void k_mix_mfma(
    const bf16* __restrict__ sampled, bf16* __restrict__ params, int m_off) {
  int bnl = blockIdx.x, g = blockIdx.y;
  int tid = threadIdx.x;
  const int w = tid >> 6, l = tid & 63;
  const int lr = l & 15, lq = l >> 4;
  __shared__ char mt[8192];
  __shared__ alignas(16) bf16 h1t[64 * 40];
  __shared__ float red[8];
  const bf16* samp = sampled + ((size_t)(m_off + bnl) * 4 + g) * 2048;
  bf16* pr = params + (size_t)bnl * 32768 + (size_t)g * 8192;

  {
    int cblk = tid >> 4, dblk = tid & 15;
    const bf16* src = pr + cblk * 256 + dblk * 4;
    bf16x4 r0 = *(const bf16x4*)(src);
    bf16x4 r1 = *(const bf16x4*)(src + 64);
    bf16x4 r2 = *(const bf16x4*)(src + 128);
    bf16x4 r3 = *(const bf16x4*)(src + 192);
    int chv = (cblk >> 1) << 4, sub = (cblk & 1) * 8;
#pragma unroll
    for (int j = 0; j < 4; j++) {
      int d = dblk * 4 + j;
      bf16x4 t = {r0[j], r1[j], r2[j], r3[j]};
      *(bf16x4*)(mt + d * 128 + (chv ^ swz(d)) + sub) = t;
    }
  }
  __syncthreads();

  f32x4 acc1[2];
  acc1[0] = (f32x4)(0.f); acc1[1] = (f32x4)(0.f);
  const int dd = w * 16 + lr;
#pragma unroll
  for (int ks = 0; ks < 2; ks++) {
    bf16x8 bfr = *(const bf16x8*)(mt + dd * 128 + ((((ks << 2) | lq) << 4) ^ swz(dd)));
#pragma unroll
    for (int i = 0; i < 2; i++) {
      bf16x8 a = *(const bf16x8*)(samp + (i * 16 + lr) * 64 + ks * 32 + lq * 8);
      acc1[i] = __builtin_amdgcn_mfma_f32_16x16x32_bf16(a, bfr, acc1[i], 0, 0, 0);
    }
  }

  {
    float s = 0.f, ss = 0.f;
#pragma unroll
    for (int i = 0; i < 2; i++)
#pragma unroll
      for (int r = 0; r < 4; r++) { float v = acc1[i][r]; s += v; ss += v * v; }
    s = wred(s); ss = wred(ss);
    if (l == 0) { red[w] = s; red[4 + w] = ss; }
    __syncthreads();
    s = red[0] + red[1] + red[2] + red[3];
    ss = red[4] + red[5] + red[6] + red[7];
    float mean = s * (1.f / 2048.f);
    float var = ss * (1.f / 2048.f) - mean * mean;
    float rs = rsqrtf(fmaxf(var, 0.f) + 1e-5f);
#pragma unroll
    for (int i = 0; i < 2; i++)
#pragma unroll
      for (int r = 0; r < 4; r++) {
        float v = (acc1[i][r] - mean) * rs;
        v = v > 0.f ? v : 0.f;
        int p = i * 16 + lq * 4 + r;
        h1t[dd * 40 + p] = (bf16)v;
      }
  }
  __syncthreads();

  f32x4 acc2[2][4];
#pragma unroll
  for (int i = 0; i < 2; i++)
#pragma unroll
    for (int j = 0; j < 4; j++) acc2[i][j] = (f32x4)(0.f);
  bf16x8 b2[4];
#pragma unroll
  for (int j = 0; j < 4; j++)
    b2[j] = *(const bf16x8*)(&h1t[(j * 16 + lr) * 40 + lq * 8]);
#pragma unroll
  for (int i = 0; i < 2; i++) {
    int o = w * 32 + i * 16 + lr;
    bf16x8 a = *(const bf16x8*)(pr + 4096 + o * 32 + lq * 8);
#pragma unroll
    for (int j = 0; j < 4; j++)
      acc2[i][j] = __builtin_amdgcn_mfma_f32_16x16x32_bf16(a, b2[j], acc2[i][j], 0, 0, 0);
  }

  {
    float s = 0.f, ss = 0.f;
#pragma unroll
    for (int i = 0; i < 2; i++)
#pragma unroll
      for (int j = 0; j < 4; j++)
#pragma unroll
        for (int r = 0; r < 4; r++) { float v = acc2[i][j][r]; s += v; ss += v * v; }
    s = wred(s); ss = wred(ss);
    if (l == 0) { red[w] = s; red[4 + w] = ss; }
    __syncthreads();
    s = red[0] + red[1] + red[2] + red[3];
    ss = red[4] + red[5] + red[6] + red[7];
    float mean = s * (1.f / 8192.f);
    float var = ss * (1.f / 8192.f) - mean * mean;
    float rs = rsqrtf(fmaxf(var, 0.f) + 1e-5f);
#pragma unroll
    for (int i = 0; i < 2; i++)
#pragma unroll
      for (int r = 0; r < 4; r++) {
        int o = w * 32 + i * 16 + lq * 4 + r;
#pragma unroll
        for (int j = 0; j < 4; j++) {
          float v = (acc2[i][j][r] - mean) * rs;
          v = v > 0.f ? v : 0.f;
          pr[o * 64 + j * 16 + lr] = (bf16)v;
        }
      }
  }
}

// ---------- MFMA final GEMM (split-K + atomics), KT = k-tiles of 64 per block ----------
__global__ __launch_bounds__(256) void k_final_mfma(
    const bf16* __restrict__ pchunk, const float* __restrict__ op_w,
    float* __restrict__ facc, int m_off, int m_cnt, int KT) {
  __shared__ char sA[8192];    // [64 rows][128 B]
  __shared__ char sW[32768];   // [256 n-rows][128 B]
  const int tid = threadIdx.x;
  const int w = tid >> 6, l = tid & 63;
  const int lr = l & 15, lq = l >> 4;
  const int m0 = blockIdx.y * 64;
  const int kb0 = blockIdx.x * (KT * 64);

  f32x4 acc[4][4];
#pragma unroll
  for (int i = 0; i < 4; i++)
#pragma unroll
    for (int j = 0; j < 4; j++) acc[i][j] = (f32x4)(0.f);

  for (int kt = 0; kt < KT; kt++) {
    const int kb = kb0 + kt * 64;

#pragma unroll
    for (int i = 0; i < 2; i++) {
      int c = tid * 2 + i;                  // 0..511
      int r = c >> 3, kc = c & 7;
      int gm = m0 + r; gm = (gm < m_cnt) ? gm : (m_cnt - 1);
      f32x4 v = *(const f32x4*)(pchunk + (size_t)gm * 32768 + kb + kc * 8);
      *(f32x4*)(sA + r * 128 + ((kc << 4) ^ swz(r))) = v;
    }

#pragma unroll
    for (int i = 0; i < 4; i++) {
      int kblk = i * 4 + w;                 // 0..15, k = kblk*4 + 0..3
      const float* src = op_w + (size_t)(kb + kblk * 4) * 256 + l * 4;
      f32x4 r0 = *(const f32x4*)(src);
      f32x4 r1 = *(const f32x4*)(src + 256);
      f32x4 r2 = *(const f32x4*)(src + 512);
      f32x4 r3 = *(const f32x4*)(src + 768);
      int chv = (kblk >> 1) << 4;
      int sub = (kblk & 1) * 8;
#pragma unroll
      for (int j = 0; j < 4; j++) {
        int n = l * 4 + j;
        bf16x4 t = {(bf16)r0[j], (bf16)r1[j], (bf16)r2[j], (bf16)r3[j]};
        *(bf16x4*)(sW + n * 128 + (chv ^ swz(n)) + sub) = t;
      }
    }
    __syncthreads();

#pragma unroll
    for (int ks = 0; ks < 2; ks++) {
      bf16x8 a[4], b[4];
      int ch = (ks * 4 + lq) << 4;
#pragma unroll
      for (int i = 0; i < 4; i++) {
        int row = i * 16 + lr;
        a[i] = *(const bf16x8*)(sA + row * 128 + (ch ^ swz(row)));
      }
#pragma unroll
      for (int j = 0; j < 4; j++) {
        int n = w * 64 + j * 16 + lr;
        b[j] = *(const bf16x8*)(sW + n * 128 + (ch ^ swz(n)));
      }
#pragma unroll
      for (int i = 0; i < 4; i++)
#pragma unroll
        for (int j = 0; j < 4; j++)
          acc[i][j] = __builtin_amdgcn_mfma_f32_16x16x32_bf16(a[i], b[j], acc[i][j], 0, 0, 0);
    }
    __syncthreads();
  }

#pragma unroll
  for (int i = 0; i < 4; i++) {
#pragma unroll
    for (int r = 0; r < 4; r++) {
      int m = m0 + i * 16 + lq * 4 + r;
      if (m < m_cnt) {
        float* dst = facc + (size_t)(m_off + m) * 256 + w * 64 + lr;
#pragma unroll
        for (int j = 0; j < 4; j++)
          atomicAdd(dst + j * 16, acc[i][j][r]);
      }
    }
  }
}

// ---------- final LN epilogue ----------
__global__ void k_ln(const float* __restrict__ accbuf, const float* __restrict__ qf,
                     const float* __restrict__ opb, const float* __restrict__ lng,
                     const float* __restrict__ lnb, float* __restrict__ out) {
  int bn = blockIdx.x, t = threadIdx.x;
  float v = accbuf[bn * 256 + t] + qf[(size_t)bn * 256 + t] + opb[t];
  __shared__ float red[8];
  float s = wred(v), ss = wred(v * v);
  int w = t >> 6;
  if ((t & 63) == 0) { red[w] = s; red[4 + w] = ss; }
  __syncthreads();
  s = red[0] + red[1] + red[2] + red[3];
  ss = red[4] + red[5] + red[6] + red[7];
  float mean = s * (1.f / 256.f);
  float var = ss * (1.f / 256.f) - mean * mean;
  float y = (v - mean) * rsqrtf(fmaxf(var, 0.f) + 1e-5f);
  out[(size_t)bn * 256 + t] = y * lng[t] + lnb[t];
}

// ---------------- launcher ----------------
// BIG layout (needs 143,001,600 B; poison fill shows ws ~= 550 MB):
//   coords  @ 0            (1,843,200 B, fp32)
//   sampled @ 1,843,200    (9,830,400 B, bf16)   -- fallback path only
//   facc    @ 11,673,600   (614,400 B, fp32)
//   params  @ 12,288,000   (39,321,600 B, bf16)  -- all 600 queries
//   xt      @ 51,609,600   (91,392,000 B, f16)   -- all 8 (b,g) slabs
// FALLBACK if ws_size < NEEDED_BIG: 32 MB aliased layout (R3 schedule).
extern "C" void kernel_launch(void* const* d_in, const int* in_sizes, int n_in,
                              void* d_out, int out_size, void* d_ws, size_t ws_size,
                              hipStream_t stream) {
  const float* x0    = (const float*)d_in[0];
  const float* x1    = (const float*)d_in[1];
  const float* x2    = (const float*)d_in[2];
  const float* x3    = (const float*)d_in[3];
  const float* qf    = (const float*)d_in[4];
  const float* roi   = (const float*)d_in[5];
  const float* w_off = (const float*)d_in[6];
  const float* b_off = (const float*)d_in[7];
  const float* pg_w  = (const float*)d_in[8];
  const float* pg_b  = (const float*)d_in[9];
  const float* op_w  = (const float*)d_in[10];
  const float* op_b  = (const float*)d_in[11];
  const float* ln_g  = (const float*)d_in[12];
  const float* ln_b  = (const float*)d_in[13];
  float* out = (float*)d_out;

  const size_t SLAB = 5712000;              // f16 elems per (b,g) slab (89250*64)
  const size_t NEEDED_BIG  = 143001600ull;
  const size_t NEEDED_SMALL = 31948800ull;
  if (ws_size < NEEDED_SMALL) return;

  char* ws = (char*)d_ws;
  float* coords  = (float*)(ws + 0);
  bf16*  sampled = (bf16*)(ws + 1843200);
  float* facc    = (float*)(ws + 11673600);

  k_zero<<<600, 256, 0, stream>>>(facc);
  k_coords<<<600, 384, 0, stream>>>(qf, roi, w_off, b_off, coords);

  if (ws_size >= NEEDED_BIG) {
    bf16* params = (bf16*)(ws + 12288000);
    f16*  xt     = (f16*)(ws + 51609600);
    k_xpose<<<dim3(699, 1, 8), 256, 0, stream>>>(x0, x1, x2, x3, xt, 0, SLAB);
    k_params_mfma<<<dim3(128, 10), 256, 0, stream>>>(qf, pg_w, pg_b, params, 0, 600);
    k_mix_fused<<<dim3(600, 4), 256, 0, stream>>>(coords, xt, params, SLAB);
    k_final_mfma<<<dim3(64, 10), 256, 0, stream>>>(params, op_w, facc, 0, 600, 8);
  } else {
    // fallback: R3 schedule (xt aliases pchunk, 2 chunks of 300)
    bf16* pchunk = (bf16*)(ws + 12288000);
    f16*  xt     = (f16*)(ws + 12288000);
    for (int bg = 0; bg < 8; bg++) {
      k_xpose<<<dim3(699, 1, 1), 256, 0, stream>>>(x0, x1, x2, x3, xt, bg, 0);
      k_sample2<<<dim3(300, 2, 1), 256, 0, stream>>>(coords, xt, sampled, bg, 0);
    }
    for (int chunk = 0; chunk < 2; chunk++) {
      int m_off = chunk * 300, m_cnt = 300;
      k_params_mfma<<<dim3(128, 5), 256, 0, stream>>>(qf, pg_w, pg_b, pchunk, m_off, m_cnt);
      k_mix_mfma<<<dim3(300, 4), 256, 0, stream>>>(sampled, pchunk, m_off);
      k_final_mfma<<<dim3(32, 5), 256, 0, stream>>>(pchunk, op_w, facc, m_off, m_cnt, 16);
    }
  }

  k_ln<<<600, 256, 0, stream>>>(facc, qf, op_b, ln_g, ln_b, out);
}

// Round 8
// 501.213 us; speedup vs baseline: 1.0287x; 1.0287x over previous
//
#include <hip/hip_runtime.h>
#include <cstdint>
#include <cstddef>

typedef __bf16 bf16;
typedef _Float16 f16;
typedef __attribute__((ext_vector_type(8))) __bf16 bf16x8;
typedef __attribute__((ext_vector_type(4))) __bf16 bf16x4;
typedef __attribute__((ext_vector_type(4))) float f32x4;
typedef __attribute__((ext_vector_type(2))) float f32x2;
typedef __attribute__((ext_vector_type(2))) uint32_t u32x2;

#define DINL __device__ __forceinline__

DINL float wred(float v) {
#pragma unroll
  for (int m = 32; m; m >>= 1) v += __shfl_xor(v, m, 64);
  return v;
}

// chunk-level XOR swizzle (16B granules within a 128B row), returns byte offset
DINL int swz(int r) { return ((r ^ (r >> 2)) & 7) << 4; }

// ---------- zero the fp32 accumulator (capture-safe) ----------
__global__ void k_zero(float* __restrict__ p) {
  p[blockIdx.x * 256 + threadIdx.x] = 0.f;
}

// ---------- coords: off = qf@w_off + b_off ; roi math ; softmax lw ----------
__global__ void k_coords(const float* __restrict__ qf, const float* __restrict__ roi,
                         const float* __restrict__ w_off, const float* __restrict__ b_off,
                         float* __restrict__ coords) {
  int bn = blockIdx.x;
  int t = threadIdx.x; // 0..383
  __shared__ float qs[256];
  __shared__ float offs[384];
  if (t < 256) qs[t] = qf[(size_t)bn * 256 + t];
  __syncthreads();
  float acc = b_off[t];
  for (int k = 0; k < 256; k++) acc += qs[k] * w_off[k * 384 + t];
  offs[t] = acc;
  __syncthreads();
  if (t < 128) {
    float ox = offs[t * 3 + 0], oy = offs[t * 3 + 1], oz = offs[t * 3 + 2];
    float cx = roi[bn * 4 + 0], cy = roi[bn * 4 + 1];
    float z  = roi[bn * 4 + 2], rr = roi[bn * 4 + 3];
    float sx = cx + ox * exp2f(z - 0.5f * rr);
    float sy = cy + oy * exp2f(z + 0.5f * rr);
    float lvl = z + oz;
    float e[4], mx = -1e30f;
#pragma unroll
    for (int l = 0; l < 4; l++) {
      float d = lvl - 3.0f - (float)l;
      e[l] = -d * d * 0.5f;           // TAU = 2
      mx = fmaxf(mx, e[l]);
    }
    float s = 0.f;
#pragma unroll
    for (int l = 0; l < 4; l++) { e[l] = expf(e[l] - mx); s += e[l]; }
    float inv = 1.f / s;
    float* o = coords + ((size_t)bn * 128 + t) * 6;
    o[0] = sx; o[1] = sy;
#pragma unroll
    for (int l = 0; l < 4; l++) o[2 + l] = e[l] * inv;
  }
}

// ---------- transpose (b,g) slabs -> channel-last (HW_total, 64) f16 ----------
// BATCHED loads: all 16 global f32x2 into v[16] first (R6's VGPR=8 version
// serialized vmcnt chains -> 90 us @ 5% VALU; batching exposes MLP).
__global__ __launch_bounds__(256) void k_xpose(
    const float* __restrict__ x0, const float* __restrict__ x1,
    const float* __restrict__ x2, const float* __restrict__ x3,
    f16* __restrict__ xt, int bg0, size_t slab) {
  const int HWl[4]  = {67200, 16800, 4200, 1050};
  const int RB[4]   = {0, 67200, 84000, 88200};
  const float* xs[4] = {x0, x1, x2, x3};
  int bx = blockIdx.x;
  int l, t0;
  if (bx < 525)      { l = 0; t0 = 0; }
  else if (bx < 657) { l = 1; t0 = 525; }
  else if (bx < 690) { l = 2; t0 = 657; }
  else               { l = 3; t0 = 690; }
  int HW = HWl[l];
  int sp0 = (bx - t0) * 128;
  int bg = bg0 + blockIdx.z;
  int b = bg >> 2, g = bg & 3;
  const float* src = xs[l] + (size_t)(b * 256 + g * 64) * HW;
  __shared__ f16 tile[128 * 66];            // [sp][ch], pitch 66 f16 (132 B rows)
  int tid = threadIdx.x;
  int lane = tid & 63, wv = tid >> 6;
  int sp = sp0 + lane * 2;
  if (sp < HW) {                            // HW even for all levels
    f32x2 v[16];
#pragma unroll
    for (int j = 0; j < 16; j++)
      v[j] = *(const f32x2*)(src + (size_t)(wv * 16 + j) * HW + sp);
#pragma unroll
    for (int j = 0; j < 16; j++) {
      int ch = wv * 16 + j;
      tile[(lane * 2 + 0) * 66 + ch] = (f16)v[j][0];
      tile[(lane * 2 + 1) * 66 + ch] = (f16)v[j][1];
    }
  }
  __syncthreads();
  f16* dst = xt + slab * blockIdx.z + (size_t)(RB[l] + sp0) * 64;
  int c4 = tid & 15, srow = tid >> 4;
  const uint32_t* tp = (const uint32_t*)(&tile[0]);   // 33 dwords per row
  uint32_t pk[16];
#pragma unroll
  for (int it = 0; it < 8; it++) {
    int s = it * 16 + srow;
    pk[it * 2 + 0] = tp[s * 33 + c4 * 2];
    pk[it * 2 + 1] = tp[s * 33 + c4 * 2 + 1];
  }
#pragma unroll
  for (int it = 0; it < 8; it++) {
    int s = it * 16 + srow;
    if (sp0 + s < HW) {
      u32x2 q; q[0] = pk[it * 2]; q[1] = pk[it * 2 + 1];
      *(u32x2*)(dst + (size_t)s * 64 + c4 * 4) = q;
    }
  }
}

// ---------- sampling from channel-last f16 ----------
__global__ __launch_bounds__(256) void k_sample2(
    const float* __restrict__ coords, const f16* __restrict__ xt,
    bf16* __restrict__ sampled, int bg0, size_t slab) {
  const int   Wl[4] = {336, 168, 84, 42};
  const int   Hl[4] = {200, 100, 50, 25};
  const int   RB[4] = {0, 67200, 84000, 88200};
  const float IS[4] = {0.25f, 0.125f, 0.0625f, 0.03125f};
  int bg = bg0 + blockIdx.z;
  int b = bg >> 2, g = bg & 3;
  int bn = b * 300 + blockIdx.x;
  const f16* xts = xt + slab * blockIdx.z;
  int c = threadIdx.x & 63, pp = threadIdx.x >> 6;
#pragma unroll
  for (int p8i = 0; p8i < 4; p8i++) {
    int p8 = blockIdx.y * 4 + p8i;
    int p = p8 * 4 + pp;
    const float* cd = coords + ((size_t)bn * 128 + g * 32 + p) * 6;
    float sx = cd[0], sy = cd[1];
    float acc = 0.f;
#pragma unroll
    for (int l = 0; l < 4; l++) {
      float wl = cd[2 + l];
      int W = Wl[l], H = Hl[l];
      float xf = sx * IS[l] - 0.5f;
      float yf = sy * IS[l] - 0.5f;
      float xx0 = floorf(xf), yy0 = floorf(yf);
      float fx = xf - xx0, fy = yf - yy0;
      int xi = (int)xx0, yi = (int)yy0;
      const f16* base = xts + (size_t)RB[l] * 64 + c;
      float v = 0.f;
      if (xi >= 0     && xi < W     && yi >= 0     && yi < H)
        v += (1.f - fx) * (1.f - fy) * (float)base[(size_t)(yi * W + xi) * 64];
      if (xi + 1 >= 0 && xi + 1 < W && yi >= 0     && yi < H)
        v += fx * (1.f - fy) * (float)base[(size_t)(yi * W + xi + 1) * 64];
      if (xi >= 0     && xi < W     && yi + 1 >= 0 && yi + 1 < H)
        v += (1.f - fx) * fy * (float)base[(size_t)((yi + 1) * W + xi) * 64];
      if (xi + 1 >= 0 && xi + 1 < W && yi + 1 >= 0 && yi + 1 < H)
        v += fx * fy * (float)base[(size_t)((yi + 1) * W + xi + 1) * 64];
      acc += wl * v;
    }
    sampled[(((size_t)bn * 4 + g) * 32 + p) * 64 + c] = (bf16)acc;
  }
}

// ---------- MFMA params GEMM: pchunk[m][a] = sum_k qf[m_off+m][k]*pg_w[k][a] + pg_b[a]
__global__ __launch_bounds__(256) void k_params_mfma(
    const float* __restrict__ qf, const float* __restrict__ pg_w,
    const float* __restrict__ pg_b, bf16* __restrict__ pchunk,
    int m_off, int m_cnt) {
  __shared__ char sA[8192];    // [64 rows][128 B]
  __shared__ char sW[32768];   // [256 n-rows][128 B]
  const int tid = threadIdx.x;
  const int w = tid >> 6, l = tid & 63;
  const int lr = l & 15, lq = l >> 4;
  const int m0 = blockIdx.y * 64;
  const int n0 = blockIdx.x * 256;

  f32x4 acc[4][4];
#pragma unroll
  for (int i = 0; i < 4; i++)
#pragma unroll
    for (int j = 0; j < 4; j++) acc[i][j] = (f32x4)(0.f);

  for (int kt = 0; kt < 4; kt++) {
    const int kb = kt * 64;

#pragma unroll
    for (int i = 0; i < 2; i++) {
      int c = tid * 2 + i;                  // 16B chunk id, 0..511
      int r = c >> 3, kc = c & 7;
      int gm = m0 + r; gm = (gm < m_cnt) ? gm : (m_cnt - 1);
      const float* src = qf + (size_t)(m_off + gm) * 256 + kb + kc * 8;
      f32x4 v0 = *(const f32x4*)src;
      f32x4 v1 = *(const f32x4*)(src + 4);
      bf16x8 t = {(bf16)v0[0], (bf16)v0[1], (bf16)v0[2], (bf16)v0[3],
                  (bf16)v1[0], (bf16)v1[1], (bf16)v1[2], (bf16)v1[3]};
      *(bf16x8*)(sA + r * 128 + ((kc << 4) ^ swz(r))) = t;
    }

#pragma unroll
    for (int i = 0; i < 4; i++) {
      int kblk = i * 4 + w;                 // 0..15, k = kblk*4 + 0..3
      const float* src = pg_w + (size_t)(kb + kblk * 4) * 32768 + n0 + l * 4;
      f32x4 r0 = *(const f32x4*)(src);
      f32x4 r1 = *(const f32x4*)(src + 32768);
      f32x4 r2 = *(const f32x4*)(src + 65536);
      f32x4 r3 = *(const f32x4*)(src + 98304);
      int chv = (kblk >> 1) << 4;
      int sub = (kblk & 1) * 8;
#pragma unroll
      for (int j = 0; j < 4; j++) {
        int n = l * 4 + j;
        bf16x4 t = {(bf16)r0[j], (bf16)r1[j], (bf16)r2[j], (bf16)r3[j]};
        *(bf16x4*)(sW + n * 128 + (chv ^ swz(n)) + sub) = t;
      }
    }
    __syncthreads();

#pragma unroll
    for (int ks = 0; ks < 2; ks++) {
      bf16x8 a[4], b[4];
      int ch = (ks * 4 + lq) << 4;
#pragma unroll
      for (int i = 0; i < 4; i++) {
        int row = i * 16 + lr;
        a[i] = *(const bf16x8*)(sA + row * 128 + (ch ^ swz(row)));
      }
#pragma unroll
      for (int j = 0; j < 4; j++) {
        int nn = w * 64 + j * 16 + lr;
        b[j] = *(const bf16x8*)(sW + nn * 128 + (ch ^ swz(nn)));
      }
#pragma unroll
      for (int i = 0; i < 4; i++)
#pragma unroll
        for (int j = 0; j < 4; j++)
          acc[i][j] = __builtin_amdgcn_mfma_f32_16x16x32_bf16(a[i], b[j], acc[i][j], 0, 0, 0);
    }
    __syncthreads();
  }

#pragma unroll
  for (int i = 0; i < 4; i++) {
#pragma unroll
    for (int r = 0; r < 4; r++) {
      int m = m0 + i * 16 + lq * 4 + r;
      if (m < m_cnt) {
        bf16* dst = pchunk + (size_t)m * 32768 + n0 + w * 64 + lr;
#pragma unroll
        for (int j = 0; j < 4; j++) {
          int n = n0 + w * 64 + j * 16 + lr;
          dst[j * 16] = (bf16)(acc[i][j][r] + pg_b[n]);
        }
      }
    }
  }
}

// ---------- MFMA mixing: one block per (bn_local, g), 4 waves share ----------
__global__ __launch_bounds__(256) void k_mix_mfma(
    const bf16* __restrict__ sampled, bf16* __restrict__ params, int m_off) {
  int bnl = blockIdx.x, g = blockIdx.y;
  int tid = threadIdx.x;
  const int w = tid >> 6, l = tid & 63;
  const int lr = l & 15, lq = l >> 4;
  __shared__ char mt[8192];
  __shared__ alignas(16) bf16 h1t[64 * 40];
  __shared__ float red[8];
  const bf16* samp = sampled + ((size_t)(m_off + bnl) * 4 + g) * 2048;
  bf16* pr = params + (size_t)bnl * 32768 + (size_t)g * 8192;

  {
    int cblk = tid >> 4, dblk = tid & 15;
    const bf16* src = pr + cblk * 256 + dblk * 4;
    bf16x4 r0 = *(const bf16x4*)(src);
    bf16x4 r1 = *(const bf16x4*)(src + 64);
    bf16x4 r2 = *(const bf16x4*)(src + 128);
    bf16x4 r3 = *(const bf16x4*)(src + 192);
    int chv = (cblk >> 1) << 4, sub = (cblk & 1) * 8;
#pragma unroll
    for (int j = 0; j < 4; j++) {
      int d = dblk * 4 + j;
      bf16x4 t = {r0[j], r1[j], r2[j], r3[j]};
      *(bf16x4*)(mt + d * 128 + (chv ^ swz(d)) + sub) = t;
    }
  }
  __syncthreads();

  f32x4 acc1[2];
  acc1[0] = (f32x4)(0.f); acc1[1] = (f32x4)(0.f);
  const int dd = w * 16 + lr;
#pragma unroll
  for (int ks = 0; ks < 2; ks++) {
    bf16x8 bfr = *(const bf16x8*)(mt + dd * 128 + ((((ks << 2) | lq) << 4) ^ swz(dd)));
#pragma unroll
    for (int i = 0; i < 2; i++) {
      bf16x8 a = *(const bf16x8*)(samp + (i * 16 + lr) * 64 + ks * 32 + lq * 8);
      acc1[i] = __builtin_amdgcn_mfma_f32_16x16x32_bf16(a, bfr, acc1[i], 0, 0, 0);
    }
  }

  {
    float s = 0.f, ss = 0.f;
#pragma unroll
    for (int i = 0; i < 2; i++)
#pragma unroll
      for (int r = 0; r < 4; r++) { float v = acc1[i][r]; s += v; ss += v * v; }
    s = wred(s); ss = wred(ss);
    if (l == 0) { red[w] = s; red[4 + w] = ss; }
    __syncthreads();
    s = red[0] + red[1] + red[2] + red[3];
    ss = red[4] + red[5] + red[6] + red[7];
    float mean = s * (1.f / 2048.f);
    float var = ss * (1.f / 2048.f) - mean * mean;
    float rs = rsqrtf(fmaxf(var, 0.f) + 1e-5f);
#pragma unroll
    for (int i = 0; i < 2; i++)
#pragma unroll
      for (int r = 0; r < 4; r++) {
        float v = (acc1[i][r] - mean) * rs;
        v = v > 0.f ? v : 0.f;
        int p = i * 16 + lq * 4 + r;
        h1t[dd * 40 + p] = (bf16)v;
      }
  }
  __syncthreads();

  f32x4 acc2[2][4];
#pragma unroll
  for (int i = 0; i < 2; i++)
#pragma unroll
    for (int j = 0; j < 4; j++) acc2[i][j] = (f32x4)(0.f);
  bf16x8 b2[4];
#pragma unroll
  for (int j = 0; j < 4; j++)
    b2[j] = *(const bf16x8*)(&h1t[(j * 16 + lr) * 40 + lq * 8]);
#pragma unroll
  for (int i = 0; i < 2; i++) {
    int o = w * 32 + i * 16 + lr;
    bf16x8 a = *(const bf16x8*)(pr + 4096 + o * 32 + lq * 8);
#pragma unroll
    for (int j = 0; j < 4; j++)
      acc2[i][j] = __builtin_amdgcn_mfma_f32_16x16x32_bf16(a, b2[j], acc2[i][j], 0, 0, 0);
  }

  {
    float s = 0.f, ss = 0.f;
#pragma unroll
    for (int i = 0; i < 2; i++)
#pragma unroll
      for (int j = 0; j < 4; j++)
#pragma unroll
        for (int r = 0; r < 4; r++) { float v = acc2[i][j][r]; s += v; ss += v * v; }
    s = wred(s); ss = wred(ss);
    if (l == 0) { red[w] = s; red[4 + w] = ss; }
    __syncthreads();   // also orders all waves' S reads before in-place overwrite
    s = red[0] + red[1] + red[2] + red[3];
    ss = red[4] + red[5] + red[6] + red[7];
    float mean = s * (1.f / 8192.f);
    float var = ss * (1.f / 8192.f) - mean * mean;
    float rs = rsqrtf(fmaxf(var, 0.f) + 1e-5f);
#pragma unroll
    for (int i = 0; i < 2; i++)
#pragma unroll
      for (int r = 0; r < 4; r++) {
        int o = w * 32 + i * 16 + lq * 4 + r;
#pragma unroll
        for (int j = 0; j < 4; j++) {
          float v = (acc2[i][j][r] - mean) * rs;
          v = v > 0.f ? v : 0.f;
          pr[o * 64 + j * 16 + lr] = (bf16)v;
        }
      }
  }
}

// ---------- MFMA final GEMM (split-K + atomics), KT = k-tiles of 64 per block ----------
__global__ __launch_bounds__(256) void k_final_mfma(
    const bf16* __restrict__ pchunk, const float* __restrict__ op_w,
    float* __restrict__ facc, int m_off, int m_cnt, int KT) {
  __shared__ char sA[8192];    // [64 rows][128 B]
  __shared__ char sW[32768];   // [256 n-rows][128 B]
  const int tid = threadIdx.x;
  const int w = tid >> 6, l = tid & 63;
  const int lr = l & 15, lq = l >> 4;
  const int m0 = blockIdx.y * 64;
  const int kb0 = blockIdx.x * (KT * 64);

  f32x4 acc[4][4];
#pragma unroll
  for (int i = 0; i < 4; i++)
#pragma unroll
    for (int j = 0; j < 4; j++) acc[i][j] = (f32x4)(0.f);

  for (int kt = 0; kt < KT; kt++) {
    const int kb = kb0 + kt * 64;

#pragma unroll
    for (int i = 0; i < 2; i++) {
      int c = tid * 2 + i;                  // 0..511
      int r = c >> 3, kc = c & 7;
      int gm = m0 + r; gm = (gm < m_cnt) ? gm : (m_cnt - 1);
      f32x4 v = *(const f32x4*)(pchunk + (size_t)gm * 32768 + kb + kc * 8);
      *(f32x4*)(sA + r * 128 + ((kc << 4) ^ swz(r))) = v;
    }

#pragma unroll
    for (int i = 0; i < 4; i++) {
      int kblk = i * 4 + w;                 // 0..15, k = kblk*4 + 0..3
      const float* src = op_w + (size_t)(kb + kblk * 4) * 256 + l * 4;
      f32x4 r0 = *(const f32x4*)(src);
      f32x4 r1 = *(const f32x4*)(src + 256);
      f32x4 r2 = *(const f32x4*)(src + 512);
      f32x4 r3 = *(const f32x4*)(src + 768);
      int chv = (kblk >> 1) << 4;
      int sub = (kblk & 1) * 8;
#pragma unroll
      for (int j = 0; j < 4; j++) {
        int n = l * 4 + j;
        bf16x4 t = {(bf16)r0[j], (bf16)r1[j], (bf16)r2[j], (bf16)r3[j]};
        *(bf16x4*)(sW + n * 128 + (chv ^ swz(n)) + sub) = t;
      }
    }
    __syncthreads();

#pragma unroll
    for (int ks = 0; ks < 2; ks++) {
      bf16x8 a[4], b[4];
      int ch = (ks * 4 + lq) << 4;
#pragma unroll
      for (int i = 0; i < 4; i++) {
        int row = i * 16 + lr;
        a[i] = *(const bf16x8*)(sA + row * 128 + (ch ^ swz(row)));
      }
#pragma unroll
      for (int j = 0; j < 4; j++) {
        int n = w * 64 + j * 16 + lr;
        b[j] = *(const bf16x8*)(sW + n * 128 + (ch ^ swz(n)));
      }
#pragma unroll
      for (int i = 0; i < 4; i++)
#pragma unroll
        for (int j = 0; j < 4; j++)
          acc[i][j] = __builtin_amdgcn_mfma_f32_16x16x32_bf16(a[i], b[j], acc[i][j], 0, 0, 0);
    }
    __syncthreads();
  }

#pragma unroll
  for (int i = 0; i < 4; i++) {
#pragma unroll
    for (int r = 0; r < 4; r++) {
      int m = m0 + i * 16 + lq * 4 + r;
      if (m < m_cnt) {
        float* dst = facc + (size_t)(m_off + m) * 256 + w * 64 + lr;
#pragma unroll
        for (int j = 0; j < 4; j++)
          atomicAdd(dst + j * 16, acc[i][j][r]);
      }
    }
  }
}

// ---------- final LN epilogue ----------
__global__ void k_ln(const float* __restrict__ accbuf, const float* __restrict__ qf,
                     const float* __restrict__ opb, const float* __restrict__ lng,
                     const float* __restrict__ lnb, float* __restrict__ out) {
  int bn = blockIdx.x, t = threadIdx.x;
  float v = accbuf[bn * 256 + t] + qf[(size_t)bn * 256 + t] + opb[t];
  __shared__ float red[8];
  float s = wred(v), ss = wred(v * v);
  int w = t >> 6;
  if ((t & 63) == 0) { red[w] = s; red[4 + w] = ss; }
  __syncthreads();
  s = red[0] + red[1] + red[2] + red[3];
  ss = red[4] + red[5] + red[6] + red[7];
  float mean = s * (1.f / 256.f);
  float var = ss * (1.f / 256.f) - mean * mean;
  float y = (v - mean) * rsqrtf(fmaxf(var, 0.f) + 1e-5f);
  out[(size_t)bn * 256 + t] = y * lng[t] + lnb[t];
}

// ---------------- launcher ----------------
// BIG layout (needs 143,001,600 B; poison fill shows ws ~= 550 MB):
//   coords  @ 0            (1,843,200 B, fp32)
//   sampled @ 1,843,200    (9,830,400 B, bf16)
//   facc    @ 11,673,600   (614,400 B, fp32)
//   params  @ 12,288,000   (39,321,600 B, bf16)  -- all 600 queries
//   xt      @ 51,609,600   (91,392,000 B, f16)   -- all 8 (b,g) slabs
// FALLBACK if ws_size < NEEDED_BIG: 32 MB aliased layout (R3 schedule).
extern "C" void kernel_launch(void* const* d_in, const int* in_sizes, int n_in,
                              void* d_out, int out_size, void* d_ws, size_t ws_size,
                              hipStream_t stream) {
  const float* x0    = (const float*)d_in[0];
  const float* x1    = (const float*)d_in[1];
  const float* x2    = (const float*)d_in[2];
  const float* x3    = (const float*)d_in[3];
  const float* qf    = (const float*)d_in[4];
  const float* roi   = (const float*)d_in[5];
  const float* w_off = (const float*)d_in[6];
  const float* b_off = (const float*)d_in[7];
  const float* pg_w  = (const float*)d_in[8];
  const float* pg_b  = (const float*)d_in[9];
  const float* op_w  = (const float*)d_in[10];
  const float* op_b  = (const float*)d_in[11];
  const float* ln_g  = (const float*)d_in[12];
  const float* ln_b  = (const float*)d_in[13];
  float* out = (float*)d_out;

  const size_t SLAB = 5712000;              // f16 elems per (b,g) slab (89250*64)
  const size_t NEEDED_BIG  = 143001600ull;
  const size_t NEEDED_SMALL = 31948800ull;
  if (ws_size < NEEDED_SMALL) return;

  char* ws = (char*)d_ws;
  float* coords  = (float*)(ws + 0);
  bf16*  sampled = (bf16*)(ws + 1843200);
  float* facc    = (float*)(ws + 11673600);

  k_zero<<<600, 256, 0, stream>>>(facc);
  k_coords<<<600, 384, 0, stream>>>(qf, roi, w_off, b_off, coords);

  if (ws_size >= NEEDED_BIG) {
    bf16* params = (bf16*)(ws + 12288000);
    f16*  xt     = (f16*)(ws + 51609600);
    k_xpose<<<dim3(699, 1, 8), 256, 0, stream>>>(x0, x1, x2, x3, xt, 0, SLAB);
    k_sample2<<<dim3(300, 2, 8), 256, 0, stream>>>(coords, xt, sampled, 0, SLAB);
    k_params_mfma<<<dim3(128, 10), 256, 0, stream>>>(qf, pg_w, pg_b, params, 0, 600);
    k_mix_mfma<<<dim3(600, 4), 256, 0, stream>>>(sampled, params, 0);
    k_final_mfma<<<dim3(64, 10), 256, 0, stream>>>(params, op_w, facc, 0, 600, 8);
  } else {
    // fallback: R3 schedule (xt aliases pchunk, 2 chunks of 300)
    bf16* pchunk = (bf16*)(ws + 12288000);
    f16*  xt     = (f16*)(ws + 12288000);
    for (int bg = 0; bg < 8; bg++) {
      k_xpose<<<dim3(699, 1, 1), 256, 0, stream>>>(x0, x1, x2, x3, xt, bg, 0);
      k_sample2<<<dim3(300, 2, 1), 256, 0, stream>>>(coords, xt, sampled, bg, 0);
    }
    for (int chunk = 0; chunk < 2; chunk++) {
      int m_off = chunk * 300, m_cnt = 300;
      k_params_mfma<<<dim3(128, 5), 256, 0, stream>>>(qf, pg_w, pg_b, pchunk, m_off, m_cnt);
      k_mix_mfma<<<dim3(300, 4), 256, 0, stream>>>(sampled, pchunk, m_off);
      k_final_mfma<<<dim3(32, 5), 256, 0, stream>>>(pchunk, op_w, facc, m_off, m_cnt, 16);
    }
  }

  k_ln<<<600, 256, 0, stream>>>(facc, qf, op_b, ln_g, ln_b, out);
}